// Round 1
// baseline (602.565 us; speedup 1.0000x reference)
//
#include <hip/hip_runtime.h>

#define Bn 64
#define Cn 64
#define Hn 56
#define Wn 56
#define WP 58          // padded row width (w = -1 .. 56)
#define RB 2           // output rows per block
#define HB (Hn / RB)   // 28 row-blocks
#define NBLK (Bn * HB) // 1792 blocks

__device__ __forceinline__ float clamp8(float v) {
    return fminf(fmaxf(v, -128.f), 127.f);
}

// ---------------- Kernel 1: conv1 + requant + bn1 + requant -> int8 mid ----
__global__ __launch_bounds__(256, 2) void qbb_conv1(
    const float* __restrict__ x, const float* __restrict__ w1,
    const float* __restrict__ b1, const float* __restrict__ g1,
    const float* __restrict__ be1,
    const int* __restrict__ p_zx, const int* __restrict__ p_zm,
    const int* __restrict__ p_M0c1, const int* __restrict__ p_shc1,
    const int* __restrict__ M0b1, const int* __restrict__ shb1,
    signed char* __restrict__ mid)
{
    __shared__ float in_s[RB + 2][Cn][WP];
    const int blk = blockIdx.x;
    const int n  = blk / HB;
    const int h0 = (blk % HB) * RB;
    const int tid = threadIdx.x;
    const float zx = (float)(*p_zx);
    const float zm = (float)(*p_zm);

    // stage (x - zx) rows h0-1 .. h0+2, zero-padded, into LDS
    const int total = (RB + 2) * Cn * WP;
    for (int idx = tid; idx < total; idx += 256) {
        int r   = idx / (Cn * WP);
        int rem = idx - r * (Cn * WP);
        int ci  = rem / WP;
        int wp  = rem - ci * WP;
        int hh  = h0 - 1 + r;
        int w   = wp - 1;
        float v = 0.f;
        if ((unsigned)hh < (unsigned)Hn && (unsigned)w < (unsigned)Wn)
            v = x[((n * Cn + ci) * Hn + hh) * Wn + w] - zx;
        in_s[r][ci][wp] = v;
    }
    __syncthreads();

    const int hsub  = tid >> 7;        // 0..1
    const int cog   = (tid >> 2) & 31; // 0..31
    const int co    = cog * 2;
    const int g     = tid & 3;
    const int wbase = g * 14;

    float accA[14], accB[14];
#pragma unroll
    for (int r = 0; r < 14; ++r) { accA[r] = 0.f; accB[r] = 0.f; }

    for (int ci = 0; ci < Cn; ++ci) {
#pragma unroll
        for (int kh = 0; kh < 3; ++kh) {
            const float* rowp = &in_s[hsub + kh][ci][wbase];
            float rv[16];
#pragma unroll
            for (int j = 0; j < 16; ++j) rv[j] = rowp[j];
            const float* wpa = w1 + ((co * Cn + ci) * 3 + kh) * 3;
            const float* wpb = w1 + (((co + 1) * Cn + ci) * 3 + kh) * 3;
            float a0 = wpa[0], a1 = wpa[1], a2 = wpa[2];
            float c0 = wpb[0], c1 = wpb[1], c2 = wpb[2];
#pragma unroll
            for (int r = 0; r < 14; ++r) {
                accA[r] = fmaf(rv[r],     a0, accA[r]);
                accA[r] = fmaf(rv[r + 1], a1, accA[r]);
                accA[r] = fmaf(rv[r + 2], a2, accA[r]);
                accB[r] = fmaf(rv[r],     c0, accB[r]);
                accB[r] = fmaf(rv[r + 1], c1, accB[r]);
                accB[r] = fmaf(rv[r + 2], c2, accB[r]);
            }
        }
    }

    const int h = h0 + hsub;
    const float sc1 = ldexpf((float)(*p_M0c1), -31 - (*p_shc1));

#define EPILOG1(ACC, CC)                                                     \
    {                                                                        \
        const int c = (CC);                                                  \
        const float bb = b1[c], gg = g1[c], be = be1[c];                     \
        const float sb = ldexpf((float)M0b1[c], -31 - shb1[c]);              \
        signed char* mp = mid + ((n * Cn + c) * Hn + h) * Wn + wbase;        \
        _Pragma("unroll")                                                    \
        for (int r = 0; r < 14; ++r) {                                       \
            float a = ACC[r] + bb;                                           \
            float v = clamp8(rintf(a * sc1) + zm);                           \
            float t = (v - zm) * gg + be;                                    \
            float u = clamp8(rintf(t * sb) + zm);                            \
            mp[r] = (signed char)(int)u;                                     \
        }                                                                    \
    }
    EPILOG1(accA, co)
    EPILOG1(accB, co + 1)
#undef EPILOG1
}

// ---- Kernel 2: conv2 + requant + bn2 + requant + quantized add -> f32 out --
__global__ __launch_bounds__(256, 2) void qbb_conv2(
    const signed char* __restrict__ mid, const float* __restrict__ x,
    const float* __restrict__ w2, const float* __restrict__ b2,
    const float* __restrict__ g2, const float* __restrict__ be2,
    const int* __restrict__ p_zx, const int* __restrict__ p_zm,
    const int* __restrict__ p_M0c2, const int* __restrict__ p_shc2,
    const int* __restrict__ M0b2, const int* __restrict__ shb2,
    const int* __restrict__ p_M0a1, const int* __restrict__ p_sha1,
    const int* __restrict__ p_M0a2, const int* __restrict__ p_sha2,
    const int* __restrict__ p_zadd, float* __restrict__ out)
{
    __shared__ float in_s[RB + 2][Cn][WP];
    const int blk = blockIdx.x;
    const int n  = blk / HB;
    const int h0 = (blk % HB) * RB;
    const int tid = threadIdx.x;
    const float zx = (float)(*p_zx);
    const float zm = (float)(*p_zm);

    const int total = (RB + 2) * Cn * WP;
    for (int idx = tid; idx < total; idx += 256) {
        int r   = idx / (Cn * WP);
        int rem = idx - r * (Cn * WP);
        int ci  = rem / WP;
        int wp  = rem - ci * WP;
        int hh  = h0 - 1 + r;
        int w   = wp - 1;
        float v = 0.f;
        if ((unsigned)hh < (unsigned)Hn && (unsigned)w < (unsigned)Wn)
            v = (float)mid[((n * Cn + ci) * Hn + hh) * Wn + w] - zm;
        in_s[r][ci][wp] = v;
    }
    __syncthreads();

    const int hsub  = tid >> 7;
    const int cog   = (tid >> 2) & 31;
    const int co    = cog * 2;
    const int g     = tid & 3;
    const int wbase = g * 14;

    float accA[14], accB[14];
#pragma unroll
    for (int r = 0; r < 14; ++r) { accA[r] = 0.f; accB[r] = 0.f; }

    for (int ci = 0; ci < Cn; ++ci) {
#pragma unroll
        for (int kh = 0; kh < 3; ++kh) {
            const float* rowp = &in_s[hsub + kh][ci][wbase];
            float rv[16];
#pragma unroll
            for (int j = 0; j < 16; ++j) rv[j] = rowp[j];
            const float* wpa = w2 + ((co * Cn + ci) * 3 + kh) * 3;
            const float* wpb = w2 + (((co + 1) * Cn + ci) * 3 + kh) * 3;
            float a0 = wpa[0], a1 = wpa[1], a2 = wpa[2];
            float c0 = wpb[0], c1 = wpb[1], c2 = wpb[2];
#pragma unroll
            for (int r = 0; r < 14; ++r) {
                accA[r] = fmaf(rv[r],     a0, accA[r]);
                accA[r] = fmaf(rv[r + 1], a1, accA[r]);
                accA[r] = fmaf(rv[r + 2], a2, accA[r]);
                accB[r] = fmaf(rv[r],     c0, accB[r]);
                accB[r] = fmaf(rv[r + 1], c1, accB[r]);
                accB[r] = fmaf(rv[r + 2], c2, accB[r]);
            }
        }
    }

    const int h = h0 + hsub;
    const float sc2  = ldexpf((float)(*p_M0c2), -31 - (*p_shc2));
    const float sa1  = ldexpf((float)(*p_M0a1), -31 - (*p_sha1));
    const float sa2  = ldexpf((float)(*p_M0a2), -31 - (*p_sha2));
    const float zadd = (float)(*p_zadd);

#define EPILOG2(ACC, CC)                                                     \
    {                                                                        \
        const int c = (CC);                                                  \
        const float bb = b2[c], gg = g2[c], be = be2[c];                     \
        const float sb = ldexpf((float)M0b2[c], -31 - shb2[c]);              \
        const long off = ((long)(n * Cn + c) * Hn + h) * Wn + wbase;         \
        const float* xp = x + off;                                           \
        float* op = out + off;                                               \
        _Pragma("unroll")                                                    \
        for (int r = 0; r < 14; ++r) {                                       \
            float a = ACC[r] + bb;                                           \
            float v = clamp8(rintf(a * sc2) + zm);                           \
            float t = (v - zm) * gg + be;                                    \
            float u = clamp8(rintf(t * sb) + zm);                            \
            float outr = rintf((u - zm) * sa2);                              \
            float idr  = rintf((xp[r] - zx) * sa1);                          \
            op[r] = clamp8(idr + outr + zadd);                               \
        }                                                                    \
    }
    EPILOG2(accA, co)
    EPILOG2(accB, co + 1)
#undef EPILOG2
}

extern "C" void kernel_launch(void* const* d_in, const int* in_sizes, int n_in,
                              void* d_out, int out_size, void* d_ws, size_t ws_size,
                              hipStream_t stream) {
    const float* x   = (const float*)d_in[0];
    const float* w1  = (const float*)d_in[1];
    const float* b1  = (const float*)d_in[2];
    const float* w2  = (const float*)d_in[3];
    const float* b2  = (const float*)d_in[4];
    const float* g1  = (const float*)d_in[5];
    const float* be1 = (const float*)d_in[6];
    const float* g2  = (const float*)d_in[7];
    const float* be2 = (const float*)d_in[8];
    const int* z_x   = (const int*)d_in[9];
    const int* z_mid = (const int*)d_in[10];
    const int* M0c1  = (const int*)d_in[11];
    const int* shc1  = (const int*)d_in[12];
    const int* M0b1  = (const int*)d_in[13];
    const int* shb1  = (const int*)d_in[14];
    const int* M0c2  = (const int*)d_in[15];
    const int* shc2  = (const int*)d_in[16];
    const int* M0b2  = (const int*)d_in[17];
    const int* shb2  = (const int*)d_in[18];
    const int* M0a1  = (const int*)d_in[19];
    const int* sha1  = (const int*)d_in[20];
    const int* M0a2  = (const int*)d_in[21];
    const int* sha2  = (const int*)d_in[22];
    const int* z_add = (const int*)d_in[23];

    signed char* mid = (signed char*)d_ws;  // 64*64*56*56 = 12.8 MB int8

    dim3 grid(NBLK), block(256);
    qbb_conv1<<<grid, block, 0, stream>>>(x, w1, b1, g1, be1,
                                          z_x, z_mid, M0c1, shc1, M0b1, shb1,
                                          mid);
    qbb_conv2<<<grid, block, 0, stream>>>(mid, x, w2, b2, g2, be2,
                                          z_x, z_mid, M0c2, shc2, M0b2, shb2,
                                          M0a1, sha1, M0a2, sha2, z_add,
                                          (float*)d_out);
}

// Round 2
// 218.851 us; speedup vs baseline: 2.7533x; 2.7533x over previous
//
#include <hip/hip_runtime.h>

typedef int v4i __attribute__((ext_vector_type(4)));

#define NIMG 64
#define Cc   64
#define Hh   56
#define Ww   56
#define NPIX (Hh * Ww)        // 3136
#define PS   58               // padded spatial dim
#define PROWB (PS * Cc)       // padded row bytes   = 3712
#define PIMGB (PS * PS * Cc)  // padded image bytes = 215296
#define MID_OFF ((size_t)NIMG * PIMGB)       // 13778944
#define W8_OFF  (2 * (size_t)NIMG * PIMGB)   // 27557888
#define W8SZ    (9 * 4 * 64 * 16)            // 36864 bytes per weight tensor

__device__ __forceinline__ float clamp8(float v) {
    return fminf(fmaxf(v, -128.f), 127.f);
}

// ---- pack OIHW fp32 weights into MFMA A-fragment order ---------------------
// dst[t][cb][lane][j] : co = cb*16 + (lane&15), ci = (lane>>4)*16 + j, t = kh*3+kw
__global__ __launch_bounds__(256) void qbb_pack_w(
    const float* __restrict__ w1, const float* __restrict__ w2,
    signed char* __restrict__ w8)
{
    int idx = blockIdx.x * 256 + threadIdx.x;    // 0 .. 2*W8SZ-1
    int tsel = idx / W8SZ;
    int r    = idx - tsel * W8SZ;
    const float* src = tsel ? w2 : w1;
    int j    = r & 15;
    int lane = (r >> 4) & 63;
    int cb   = (r >> 10) & 3;
    int t    = r >> 12;
    int co   = cb * 16 + (lane & 15);
    int ci   = ((lane >> 4) << 4) + j;
    w8[idx] = (signed char)(int)src[(co * 64 + ci) * 9 + t];
}

// ---- x (NCHW fp32) -> x8 (padded NHWC int8, value = x - zx) ----------------
__global__ __launch_bounds__(256) void qbb_prep(
    const float* __restrict__ x, const int* __restrict__ p_zx,
    signed char* __restrict__ x8)
{
    __shared__ signed char lds[Ww * 80];
    const int b  = blockIdx.x;
    const int n  = b / PS;
    const int hp = b - n * PS;          // 0..57 padded row index
    signed char* rowp = x8 + (size_t)(n * PS + hp) * PROWB;
    const int tid = threadIdx.x;

    if (hp == 0 || hp == PS - 1) {      // top/bottom pad rows
        if (tid < PROWB / 16) *(v4i*)(rowp + tid * 16) = v4i{0, 0, 0, 0};
        return;
    }
    const int h = hp - 1;
    const float zx = (float)(*p_zx);
    const float* xb = x + (size_t)n * Cc * NPIX + h * Ww;
    for (int idx = tid; idx < Cc * Ww; idx += 256) {
        int c = idx / Ww;
        int w = idx - c * Ww;
        float v = xb[c * NPIX + w];
        lds[w * 80 + c] = (signed char)(int)(v - zx);
    }
    __syncthreads();
    if (tid < PROWB / 16) {             // 232 chunks of 16B
        int wp = tid >> 2, c0 = (tid & 3) << 4;
        v4i val = {0, 0, 0, 0};
        if (wp > 0 && wp < PS - 1)
            val = *(const v4i*)&lds[(wp - 1) * 80 + c0];
        *(v4i*)(rowp + tid * 16) = val;
    }
}

// ---- conv1 (implicit GEMM, 9 taps x K=64) + requant + bn1 + requant --------
__global__ __launch_bounds__(256, 2) void qbb_c1(
    const signed char* __restrict__ x8, const signed char* __restrict__ w8,
    const float* __restrict__ b1, const float* __restrict__ g1,
    const float* __restrict__ be1,
    const int* __restrict__ p_M0c1, const int* __restrict__ p_shc1,
    const int* __restrict__ M0b1, const int* __restrict__ shb1,
    const int* __restrict__ p_zm,
    signed char* __restrict__ mid)
{
    const int tid  = threadIdx.x;
    const int lane = tid & 63, wid = tid >> 6;
    const int blk  = blockIdx.x;
    const int n    = blk / 49;
    const int pb   = (blk - n * 49) * 64;
    const int cb0  = (wid & 1) * 2;     // co-block base: 0 or 2
    const int t0   = (wid >> 1) * 2;    // local tile base: 0 or 2
    const int g    = lane >> 4, li = lane & 15;
    const int ko   = g << 4;

    v4i a[9][2];
#pragma unroll
    for (int t = 0; t < 9; ++t)
#pragma unroll
        for (int c = 0; c < 2; ++c)
            a[t][c] = *(const v4i*)(w8 + (((t * 4 + cb0 + c) << 6) + lane) * 16);

    const float zm  = (float)(*p_zm);
    const float sc1 = ldexpf((float)(*p_M0c1), -31 - (*p_shc1));
    float bb[2][4], gg[2][4], bee[2][4], sb[2][4];
#pragma unroll
    for (int c = 0; c < 2; ++c)
#pragma unroll
        for (int r = 0; r < 4; ++r) {
            int co = (cb0 + c) * 16 + (g << 2) + r;
            bb[c][r]  = b1[co];
            gg[c][r]  = g1[co];
            bee[c][r] = be1[co];
            sb[c][r]  = ldexpf((float)M0b1[co], -31 - shb1[co]);
        }

    const signed char* xim = x8 + (size_t)n * PIMGB;
    signed char*       mim = mid + (size_t)n * PIMGB;

    for (int ti = 0; ti < 2; ++ti) {
        const int p = pb + (t0 + ti) * 16 + li;
        const int h = p / 56, w = p - h * 56;
        const signed char* b0p = xim + (h * PS + w) * Cc + ko;
        v4i bf[9];
#pragma unroll
        for (int kh = 0; kh < 3; ++kh) {
            const signed char* bp = b0p + kh * PROWB;
            bf[kh * 3 + 0] = *(const v4i*)(bp);
            bf[kh * 3 + 1] = *(const v4i*)(bp + 64);
            bf[kh * 3 + 2] = *(const v4i*)(bp + 128);
        }
        v4i acc0 = {0, 0, 0, 0}, acc1 = {0, 0, 0, 0};
#pragma unroll
        for (int t = 0; t < 9; ++t) {
            acc0 = __builtin_amdgcn_mfma_i32_16x16x64_i8(a[t][0], bf[t], acc0, 0, 0, 0);
            acc1 = __builtin_amdgcn_mfma_i32_16x16x64_i8(a[t][1], bf[t], acc1, 0, 0, 0);
        }
        signed char* outp = mim + ((h + 1) * PS + (w + 1)) * Cc + cb0 * 16 + (g << 2);
#pragma unroll
        for (int c = 0; c < 2; ++c) {
            v4i acc = c ? acc1 : acc0;
            unsigned pk = 0;
#pragma unroll
            for (int r = 0; r < 4; ++r) {
                float aa = (float)acc[r] + bb[c][r];
                float v  = clamp8(rintf(aa * sc1) + zm);
                float tt = (v - zm) * gg[c][r] + bee[c][r];
                float u  = clamp8(rintf(tt * sb[c][r]) + zm);
                int iv = (int)(u - zm);
                pk |= (unsigned)(iv & 255) << (r * 8);
            }
            *(unsigned*)(outp + c * 16) = pk;
        }
    }
}

// ---- conv2 + requant + bn2 + requant + quantized shortcut add --------------
__global__ __launch_bounds__(256, 2) void qbb_c2(
    const signed char* __restrict__ mid, const signed char* __restrict__ w8,
    const float* __restrict__ x,
    const float* __restrict__ b2, const float* __restrict__ g2,
    const float* __restrict__ be2,
    const int* __restrict__ p_M0c2, const int* __restrict__ p_shc2,
    const int* __restrict__ M0b2, const int* __restrict__ shb2,
    const int* __restrict__ p_zm, const int* __restrict__ p_zx,
    const int* __restrict__ p_M0a1, const int* __restrict__ p_sha1,
    const int* __restrict__ p_M0a2, const int* __restrict__ p_sha2,
    const int* __restrict__ p_zadd,
    float* __restrict__ out)
{
    const int tid  = threadIdx.x;
    const int lane = tid & 63, wid = tid >> 6;
    const int blk  = blockIdx.x;
    const int n    = blk / 49;
    const int pb   = (blk - n * 49) * 64;
    const int cb0  = (wid & 1) * 2;
    const int t0   = (wid >> 1) * 2;
    const int g    = lane >> 4, li = lane & 15;
    const int ko   = g << 4;

    v4i a[9][2];
#pragma unroll
    for (int t = 0; t < 9; ++t)
#pragma unroll
        for (int c = 0; c < 2; ++c)
            a[t][c] = *(const v4i*)(w8 + (((t * 4 + cb0 + c) << 6) + lane) * 16);

    const float zm   = (float)(*p_zm);
    const float zx   = (float)(*p_zx);
    const float sc2  = ldexpf((float)(*p_M0c2), -31 - (*p_shc2));
    const float sa1  = ldexpf((float)(*p_M0a1), -31 - (*p_sha1));
    const float sa2  = ldexpf((float)(*p_M0a2), -31 - (*p_sha2));
    const float zadd = (float)(*p_zadd);
    float bb[2][4], gg[2][4], bee[2][4], sb[2][4];
#pragma unroll
    for (int c = 0; c < 2; ++c)
#pragma unroll
        for (int r = 0; r < 4; ++r) {
            int co = (cb0 + c) * 16 + (g << 2) + r;
            bb[c][r]  = b2[co];
            gg[c][r]  = g2[co];
            bee[c][r] = be2[co];
            sb[c][r]  = ldexpf((float)M0b2[co], -31 - shb2[co]);
        }

    const signed char* mim = mid + (size_t)n * PIMGB;

    for (int ti = 0; ti < 2; ++ti) {
        const int p = pb + (t0 + ti) * 16 + li;
        const int h = p / 56, w = p - h * 56;
        const signed char* b0p = mim + (h * PS + w) * Cc + ko;
        v4i bf[9];
#pragma unroll
        for (int kh = 0; kh < 3; ++kh) {
            const signed char* bp = b0p + kh * PROWB;
            bf[kh * 3 + 0] = *(const v4i*)(bp);
            bf[kh * 3 + 1] = *(const v4i*)(bp + 64);
            bf[kh * 3 + 2] = *(const v4i*)(bp + 128);
        }
        v4i acc0 = {0, 0, 0, 0}, acc1 = {0, 0, 0, 0};
#pragma unroll
        for (int t = 0; t < 9; ++t) {
            acc0 = __builtin_amdgcn_mfma_i32_16x16x64_i8(a[t][0], bf[t], acc0, 0, 0, 0);
            acc1 = __builtin_amdgcn_mfma_i32_16x16x64_i8(a[t][1], bf[t], acc1, 0, 0, 0);
        }
#pragma unroll
        for (int c = 0; c < 2; ++c) {
            v4i acc = c ? acc1 : acc0;
            const int co0 = (cb0 + c) * 16 + (g << 2);
            const float* xp = x   + (size_t)(n * 64 + co0) * NPIX + p;
            float*       op = out + (size_t)(n * 64 + co0) * NPIX + p;
#pragma unroll
            for (int r = 0; r < 4; ++r) {
                float aa  = (float)acc[r] + bb[c][r];
                float v   = clamp8(rintf(aa * sc2) + zm);
                float tt  = (v - zm) * gg[c][r] + bee[c][r];
                float u   = clamp8(rintf(tt * sb[c][r]) + zm);
                float outr = rintf((u - zm) * sa2);
                float idr  = rintf((xp[r * NPIX] - zx) * sa1);
                op[r * NPIX] = clamp8(idr + outr + zadd);
            }
        }
    }
}

extern "C" void kernel_launch(void* const* d_in, const int* in_sizes, int n_in,
                              void* d_out, int out_size, void* d_ws, size_t ws_size,
                              hipStream_t stream) {
    const float* x   = (const float*)d_in[0];
    const float* w1  = (const float*)d_in[1];
    const float* b1  = (const float*)d_in[2];
    const float* w2  = (const float*)d_in[3];
    const float* b2  = (const float*)d_in[4];
    const float* g1  = (const float*)d_in[5];
    const float* be1 = (const float*)d_in[6];
    const float* g2  = (const float*)d_in[7];
    const float* be2 = (const float*)d_in[8];
    const int* z_x   = (const int*)d_in[9];
    const int* z_mid = (const int*)d_in[10];
    const int* M0c1  = (const int*)d_in[11];
    const int* shc1  = (const int*)d_in[12];
    const int* M0b1  = (const int*)d_in[13];
    const int* shb1  = (const int*)d_in[14];
    const int* M0c2  = (const int*)d_in[15];
    const int* shc2  = (const int*)d_in[16];
    const int* M0b2  = (const int*)d_in[17];
    const int* shb2  = (const int*)d_in[18];
    const int* M0a1  = (const int*)d_in[19];
    const int* sha1  = (const int*)d_in[20];
    const int* M0a2  = (const int*)d_in[21];
    const int* sha2  = (const int*)d_in[22];
    const int* z_add = (const int*)d_in[23];

    signed char* x8  = (signed char*)d_ws;                 // 13.78 MB padded NHWC
    signed char* mid = (signed char*)d_ws + MID_OFF;       // 13.78 MB padded NHWC
    signed char* w8  = (signed char*)d_ws + W8_OFF;        // 2 x 36 KB packed frags

    hipMemsetAsync(mid, 0, (size_t)NIMG * PIMGB, stream);  // zero mid pads
    qbb_pack_w<<<dim3(2 * W8SZ / 256), dim3(256), 0, stream>>>(w1, w2, w8);
    qbb_prep<<<dim3(NIMG * PS), dim3(256), 0, stream>>>(x, z_x, x8);
    qbb_c1<<<dim3(NIMG * 49), dim3(256), 0, stream>>>(
        x8, w8, b1, g1, be1, M0c1, shc1, M0b1, shb1, z_mid, mid);
    qbb_c2<<<dim3(NIMG * 49), dim3(256), 0, stream>>>(
        mid, w8 + W8SZ, x, b2, g2, be2, M0c2, shc2, M0b2, shb2,
        z_mid, z_x, M0a1, sha1, M0a2, sha2, z_add, (float*)d_out);
}

// Round 3
// 215.838 us; speedup vs baseline: 2.7917x; 1.0140x over previous
//
#include <hip/hip_runtime.h>

typedef int   v4i __attribute__((ext_vector_type(4)));
typedef float v4f __attribute__((ext_vector_type(4)));

#define NIMG 64
#define Cc   64
#define Hh   56
#define Ww   56
#define NPIX (Hh * Ww)        // 3136
#define PS   58               // padded spatial dim
#define PROWB (PS * Cc)       // padded row bytes   = 3712
#define PIMGB (PS * PS * Cc)  // padded image bytes = 215296
#define MID_OFF ((size_t)NIMG * PIMGB)
#define IDR_OFF (2 * (size_t)NIMG * PIMGB)
#define W8_OFF  (IDR_OFF + (size_t)NIMG * NPIX * Cc)
#define W8SZ    (9 * 4 * 64 * 16)            // 36864 bytes per weight tensor

__device__ __forceinline__ float clamp8(float v) {
    return fminf(fmaxf(v, -128.f), 127.f);
}

// ---- pack OIHW fp32 weights into MFMA A-fragment order ---------------------
// dst[t][cb][lane][j] : co = cb*16 + (lane&15), ci = (lane>>4)*16 + j, t = kh*3+kw
__global__ __launch_bounds__(256) void qbb_pack_w(
    const float* __restrict__ w1, const float* __restrict__ w2,
    signed char* __restrict__ w8)
{
    int idx = blockIdx.x * 256 + threadIdx.x;    // 0 .. 2*W8SZ-1
    int tsel = idx / W8SZ;
    int r    = idx - tsel * W8SZ;
    const float* src = tsel ? w2 : w1;
    int j    = r & 15;
    int lane = (r >> 4) & 63;
    int cb   = (r >> 10) & 3;
    int t    = r >> 12;
    int co   = cb * 16 + (lane & 15);
    int ci   = ((lane >> 4) << 4) + j;
    w8[idx] = (signed char)(int)src[(co * 64 + ci) * 9 + t];
}

// ---- prep: x (NCHW f32) -> x8 (padded NHWC int8), idr8 (NHWC int8 shortcut),
//            and zero mid's pad ring ----------------------------------------
__global__ __launch_bounds__(256) void qbb_prep(
    const float* __restrict__ x, const int* __restrict__ p_zx,
    const int* __restrict__ p_M0a1, const int* __restrict__ p_sha1,
    signed char* __restrict__ x8, signed char* __restrict__ idr8,
    signed char* __restrict__ mid)
{
    __shared__ signed char xls[56 * 80];
    __shared__ signed char ils[56 * 80];
    const int b  = blockIdx.x;
    const int n  = b / PS;
    const int hp = b - n * PS;          // padded row 0..57
    const int tid = threadIdx.x;
    signed char* x8row  = x8  + (size_t)(n * PS + hp) * PROWB;
    signed char* midrow = mid + (size_t)(n * PS + hp) * PROWB;

    if (hp == 0 || hp == PS - 1) {      // full pad rows: zero x8 and mid
        if (tid < PROWB / 16) {
            *(v4i*)(x8row  + tid * 16) = v4i{0, 0, 0, 0};
            *(v4i*)(midrow + tid * 16) = v4i{0, 0, 0, 0};
        }
        return;
    }
    const int h = hp - 1;
    const float zx  = (float)(*p_zx);
    const float sa1 = ldexpf((float)(*p_M0a1), -31 - (*p_sha1));

    if (tid < 224) {                    // 16 c-quads x 14 w-quads
        const int cq = tid & 15, wq = tid >> 4;
        const int c0 = cq * 4, w0 = wq * 4;
        unsigned px[4] = {0, 0, 0, 0}, pi[4] = {0, 0, 0, 0};
#pragma unroll
        for (int j = 0; j < 4; ++j) {
            v4f f = *(const v4f*)(x + (size_t)(n * Cc + c0 + j) * NPIX + h * Ww + w0);
#pragma unroll
            for (int jw = 0; jw < 4; ++jw) {
                float v = f[jw];
                int bx = (int)(v - zx);
                int bi = (int)rintf((v - zx) * sa1);
                px[jw] |= (unsigned)(bx & 255) << (j * 8);
                pi[jw] |= (unsigned)(bi & 255) << (j * 8);
            }
        }
#pragma unroll
        for (int jw = 0; jw < 4; ++jw) {
            *(unsigned*)&xls[(w0 + jw) * 80 + c0] = px[jw];
            *(unsigned*)&ils[(w0 + jw) * 80 + c0] = pi[jw];
        }
    }
    __syncthreads();
    if (tid < 232) {                    // x8 padded row: 58 px x 64B
        const int wp = tid >> 2, c16 = (tid & 3) * 16;
        v4i v = {0, 0, 0, 0};
        if (wp >= 1 && wp <= 56) v = *(const v4i*)&xls[(wp - 1) * 80 + c16];
        *(v4i*)(x8row + tid * 16) = v;
    }
    if (tid < 224) {                    // idr8 unpadded row: 56 px x 64B
        const int w = tid >> 2, c16 = (tid & 3) * 16;
        *(v4i*)(idr8 + ((size_t)(n * NPIX) + h * Ww + w) * 64 + c16) =
            *(const v4i*)&ils[w * 80 + c16];
    }
    if (tid < 8) {                      // zero mid pad columns of this row
        const int pxl = (tid < 4) ? 0 : (PS - 1);
        *(v4i*)(midrow + pxl * 64 + (tid & 3) * 16) = v4i{0, 0, 0, 0};
    }
}

// ---- conv1 (implicit GEMM via LDS-staged tile) + requant + bn1 + requant ---
__global__ __launch_bounds__(256, 4) void qbb_c1(
    const signed char* __restrict__ x8, const signed char* __restrict__ w8,
    const float* __restrict__ b1, const float* __restrict__ g1,
    const float* __restrict__ be1,
    const int* __restrict__ p_M0c1, const int* __restrict__ p_shc1,
    const int* __restrict__ M0b1, const int* __restrict__ shb1,
    const int* __restrict__ p_zm,
    signed char* __restrict__ mid)
{
    __shared__ signed char xs[4 * 58 * 80];   // 4 padded rows, stride-80
    const int tid  = threadIdx.x;
    const int lane = tid & 63, wid = tid >> 6;
    const int blk  = blockIdx.x;
    const int n    = blk / 49;
    const int pb   = (blk - n * 49) * 64;
    const int h_lo = pb / 56;                 // first padded row to stage

    const signed char* xim = x8 + (size_t)n * PIMGB + (size_t)h_lo * PROWB;
    for (int idx = tid; idx < 4 * 232; idx += 256) {
        int rr = idx / 232, k = idx - rr * 232;
        v4i v = *(const v4i*)(xim + rr * PROWB + k * 16);
        *(v4i*)&xs[(rr * 58 + (k >> 2)) * 80 + (k & 3) * 16] = v;
    }

    const int cb0 = (wid & 1) * 2;
    const int t0  = (wid >> 1) * 2;
    const int g   = lane >> 4, li = lane & 15;

    v4i a[9][2];
#pragma unroll
    for (int t = 0; t < 9; ++t)
#pragma unroll
        for (int c = 0; c < 2; ++c)
            a[t][c] = *(const v4i*)(w8 + (((t * 4 + cb0 + c) << 6) + lane) * 16);

    const float zm  = (float)(*p_zm);
    const float sc1 = ldexpf((float)(*p_M0c1), -31 - (*p_shc1));
    float bb[2][4], gg[2][4], bee[2][4], sb[2][4];
#pragma unroll
    for (int c = 0; c < 2; ++c)
#pragma unroll
        for (int r = 0; r < 4; ++r) {
            int co = (cb0 + c) * 16 + (g << 2) + r;
            bb[c][r]  = b1[co];
            gg[c][r]  = g1[co];
            bee[c][r] = be1[co];
            sb[c][r]  = ldexpf((float)M0b1[co], -31 - shb1[co]);
        }

    __syncthreads();

    signed char* mim = mid + (size_t)n * PIMGB;
    for (int ti = 0; ti < 2; ++ti) {
        const int p = pb + (t0 + ti) * 16 + li;
        const int h = p / 56, w = p - h * 56;
        v4i bf[9];
#pragma unroll
        for (int kh = 0; kh < 3; ++kh) {
            const signed char* bp = &xs[((h - h_lo + kh) * 58 + w) * 80 + (g << 4)];
            bf[kh * 3 + 0] = *(const v4i*)(bp);
            bf[kh * 3 + 1] = *(const v4i*)(bp + 80);
            bf[kh * 3 + 2] = *(const v4i*)(bp + 160);
        }
        v4i acc0 = {0, 0, 0, 0}, acc1 = {0, 0, 0, 0};
#pragma unroll
        for (int t = 0; t < 9; ++t) {
            acc0 = __builtin_amdgcn_mfma_i32_16x16x64_i8(a[t][0], bf[t], acc0, 0, 0, 0);
            acc1 = __builtin_amdgcn_mfma_i32_16x16x64_i8(a[t][1], bf[t], acc1, 0, 0, 0);
        }
        signed char* outp = mim + ((h + 1) * PS + (w + 1)) * Cc + cb0 * 16 + (g << 2);
#pragma unroll
        for (int c = 0; c < 2; ++c) {
            v4i acc = c ? acc1 : acc0;
            unsigned pk = 0;
#pragma unroll
            for (int r = 0; r < 4; ++r) {
                float aa = (float)acc[r] + bb[c][r];
                float v  = clamp8(rintf(aa * sc1) + zm);
                float tt = (v - zm) * gg[c][r] + bee[c][r];
                float u  = clamp8(rintf(tt * sb[c][r]) + zm);
                int iv = (int)(u - zm);
                pk |= (unsigned)(iv & 255) << (r * 8);
            }
            *(unsigned*)(outp + c * 16) = pk;
        }
    }
}

// ---- conv2 + requant + bn2 + requant + quantized shortcut add --------------
__global__ __launch_bounds__(256, 4) void qbb_c2(
    const signed char* __restrict__ mid, const signed char* __restrict__ w8,
    const signed char* __restrict__ idr8,
    const float* __restrict__ b2, const float* __restrict__ g2,
    const float* __restrict__ be2,
    const int* __restrict__ p_M0c2, const int* __restrict__ p_shc2,
    const int* __restrict__ M0b2, const int* __restrict__ shb2,
    const int* __restrict__ p_zm,
    const int* __restrict__ p_M0a2, const int* __restrict__ p_sha2,
    const int* __restrict__ p_zadd,
    float* __restrict__ out)
{
    __shared__ signed char xs[4 * 58 * 80];
    const int tid  = threadIdx.x;
    const int lane = tid & 63, wid = tid >> 6;
    const int blk  = blockIdx.x;
    const int n    = blk / 49;
    const int pb   = (blk - n * 49) * 64;
    const int h_lo = pb / 56;

    const signed char* mim = mid + (size_t)n * PIMGB + (size_t)h_lo * PROWB;
    for (int idx = tid; idx < 4 * 232; idx += 256) {
        int rr = idx / 232, k = idx - rr * 232;
        v4i v = *(const v4i*)(mim + rr * PROWB + k * 16);
        *(v4i*)&xs[(rr * 58 + (k >> 2)) * 80 + (k & 3) * 16] = v;
    }

    const int cb0 = (wid & 1) * 2;
    const int t0  = (wid >> 1) * 2;
    const int g   = lane >> 4, li = lane & 15;

    v4i a[9][2];
#pragma unroll
    for (int t = 0; t < 9; ++t)
#pragma unroll
        for (int c = 0; c < 2; ++c)
            a[t][c] = *(const v4i*)(w8 + (((t * 4 + cb0 + c) << 6) + lane) * 16);

    const float zm   = (float)(*p_zm);
    const float sc2  = ldexpf((float)(*p_M0c2), -31 - (*p_shc2));
    const float sa2  = ldexpf((float)(*p_M0a2), -31 - (*p_sha2));
    const float zadd = (float)(*p_zadd);
    float bb[2][4], gg[2][4], bee[2][4], sb[2][4];
#pragma unroll
    for (int c = 0; c < 2; ++c)
#pragma unroll
        for (int r = 0; r < 4; ++r) {
            int co = (cb0 + c) * 16 + (g << 2) + r;
            bb[c][r]  = b2[co];
            gg[c][r]  = g2[co];
            bee[c][r] = be2[co];
            sb[c][r]  = ldexpf((float)M0b2[co], -31 - shb2[co]);
        }

    __syncthreads();

    for (int ti = 0; ti < 2; ++ti) {
        const int p = pb + (t0 + ti) * 16 + li;
        const int h = p / 56, w = p - h * 56;
        v4i bf[9];
#pragma unroll
        for (int kh = 0; kh < 3; ++kh) {
            const signed char* bp = &xs[((h - h_lo + kh) * 58 + w) * 80 + (g << 4)];
            bf[kh * 3 + 0] = *(const v4i*)(bp);
            bf[kh * 3 + 1] = *(const v4i*)(bp + 80);
            bf[kh * 3 + 2] = *(const v4i*)(bp + 160);
        }
        v4i acc0 = {0, 0, 0, 0}, acc1 = {0, 0, 0, 0};
#pragma unroll
        for (int t = 0; t < 9; ++t) {
            acc0 = __builtin_amdgcn_mfma_i32_16x16x64_i8(a[t][0], bf[t], acc0, 0, 0, 0);
            acc1 = __builtin_amdgcn_mfma_i32_16x16x64_i8(a[t][1], bf[t], acc1, 0, 0, 0);
        }
#pragma unroll
        for (int c = 0; c < 2; ++c) {
            v4i acc = c ? acc1 : acc0;
            const int co0 = (cb0 + c) * 16 + (g << 2);
            unsigned id4 = *(const unsigned*)(idr8 + ((size_t)(n * NPIX) + p) * 64 + co0);
            float* op = out + ((size_t)(n * Cc + co0)) * NPIX + p;
#pragma unroll
            for (int r = 0; r < 4; ++r) {
                float aa  = (float)acc[r] + bb[c][r];
                float v   = clamp8(rintf(aa * sc2) + zm);
                float tt  = (v - zm) * gg[c][r] + bee[c][r];
                float u   = clamp8(rintf(tt * sb[c][r]) + zm);
                float outr = rintf((u - zm) * sa2);
                float idr  = (float)(signed char)(id4 >> (r * 8));
                op[r * NPIX] = clamp8(idr + outr + zadd);
            }
        }
    }
}

extern "C" void kernel_launch(void* const* d_in, const int* in_sizes, int n_in,
                              void* d_out, int out_size, void* d_ws, size_t ws_size,
                              hipStream_t stream) {
    const float* x   = (const float*)d_in[0];
    const float* w1  = (const float*)d_in[1];
    const float* b1  = (const float*)d_in[2];
    const float* w2  = (const float*)d_in[3];
    const float* b2  = (const float*)d_in[4];
    const float* g1  = (const float*)d_in[5];
    const float* be1 = (const float*)d_in[6];
    const float* g2  = (const float*)d_in[7];
    const float* be2 = (const float*)d_in[8];
    const int* z_x   = (const int*)d_in[9];
    const int* z_mid = (const int*)d_in[10];
    const int* M0c1  = (const int*)d_in[11];
    const int* shc1  = (const int*)d_in[12];
    const int* M0b1  = (const int*)d_in[13];
    const int* shb1  = (const int*)d_in[14];
    const int* M0c2  = (const int*)d_in[15];
    const int* shc2  = (const int*)d_in[16];
    const int* M0b2  = (const int*)d_in[17];
    const int* shb2  = (const int*)d_in[18];
    const int* M0a1  = (const int*)d_in[19];
    const int* sha1  = (const int*)d_in[20];
    const int* M0a2  = (const int*)d_in[21];
    const int* sha2  = (const int*)d_in[22];
    const int* z_add = (const int*)d_in[23];

    signed char* x8   = (signed char*)d_ws;
    signed char* mid  = (signed char*)d_ws + MID_OFF;
    signed char* idr8 = (signed char*)d_ws + IDR_OFF;
    signed char* w8   = (signed char*)d_ws + W8_OFF;

    qbb_pack_w<<<dim3(2 * W8SZ / 256), dim3(256), 0, stream>>>(w1, w2, w8);
    qbb_prep<<<dim3(NIMG * PS), dim3(256), 0, stream>>>(x, z_x, M0a1, sha1,
                                                        x8, idr8, mid);
    qbb_c1<<<dim3(NIMG * 49), dim3(256), 0, stream>>>(
        x8, w8, b1, g1, be1, M0c1, shc1, M0b1, shb1, z_mid, mid);
    qbb_c2<<<dim3(NIMG * 49), dim3(256), 0, stream>>>(
        mid, w8 + W8SZ, idr8, b2, g2, be2, M0c2, shc2, M0b2, shb2,
        z_mid, M0a2, sha2, z_add, (float*)d_out);
}

// Round 4
// 197.670 us; speedup vs baseline: 3.0483x; 1.0919x over previous
//
#include <hip/hip_runtime.h>

typedef int   v4i __attribute__((ext_vector_type(4)));
typedef float v4f __attribute__((ext_vector_type(4)));

#define NIMG 64
#define Cc   64
#define NPIX 3136
#define W8SZ (9 * 4 * 64 * 16)   // 36864 B per packed weight tensor

#define RBK   4                  // output rows per block
#define TILES 14                 // 56 / RBK row-tiles per image
#define XROWS 8                  // RBK + 4 staged x rows
#define MROWS 6                  // RBK + 2 mid rows
#define WPITCH 80                // LDS bytes per pixel (64 data + 16 pad)
#define ROWP  (58 * WPITCH)      // LDS bytes per padded row = 4640

__device__ __forceinline__ float clamp8(float v) {
    return fminf(fmaxf(v, -128.f), 127.f);
}

// ---- pack OIHW fp32 weights into MFMA A-fragment order ---------------------
// dst[t][cb][lane][j] : co = cb*16 + (lane&15), ci = (lane>>4)*16 + j, t = kh*3+kw
__global__ __launch_bounds__(256) void qbb_pack_w(
    const float* __restrict__ w1, const float* __restrict__ w2,
    signed char* __restrict__ w8)
{
    int idx = blockIdx.x * 256 + threadIdx.x;    // 0 .. 2*W8SZ-1
    int tsel = idx / W8SZ;
    int r    = idx - tsel * W8SZ;
    const float* src = tsel ? w2 : w1;
    int j    = r & 15;
    int lane = (r >> 4) & 63;
    int cb   = (r >> 10) & 3;
    int t    = r >> 12;
    int co   = cb * 16 + (lane & 15);
    int ci   = ((lane >> 4) << 4) + j;
    w8[idx] = (signed char)(int)src[(co * 64 + ci) * 9 + t];
}

// ---- fully fused: stage x -> conv1+bn1 (mid in LDS) -> conv2+bn2+add -------
__global__ __launch_bounds__(256, 2) void qbb_fused(
    const float* __restrict__ x, const signed char* __restrict__ w8,
    const float* __restrict__ b1, const float* __restrict__ g1,
    const float* __restrict__ be1,
    const float* __restrict__ b2, const float* __restrict__ g2,
    const float* __restrict__ be2,
    const int* __restrict__ p_zx, const int* __restrict__ p_zm,
    const int* __restrict__ p_M0c1, const int* __restrict__ p_shc1,
    const int* __restrict__ M0b1, const int* __restrict__ shb1,
    const int* __restrict__ p_M0c2, const int* __restrict__ p_shc2,
    const int* __restrict__ M0b2, const int* __restrict__ shb2,
    const int* __restrict__ p_M0a1, const int* __restrict__ p_sha1,
    const int* __restrict__ p_M0a2, const int* __restrict__ p_sha2,
    const int* __restrict__ p_zadd,
    float* __restrict__ out)
{
    __shared__ signed char xs[XROWS * ROWP];   // 37120 B: x-zx int8, padded
    __shared__ signed char ms[MROWS * ROWP];   // 27840 B: mid int8, padded

    const int tid  = threadIdx.x;
    const int lane = tid & 63, wid = tid >> 6;
    const int blk  = blockIdx.x;
    const int n    = blk / TILES;
    const int m0   = (blk - n * TILES) * RBK;  // first output row (content)

    // ---- zero LDS (covers all pads / out-of-image rows) ----
    for (int i = tid; i < (XROWS * ROWP) / 16; i += 256) ((v4i*)xs)[i] = v4i{0, 0, 0, 0};
    for (int i = tid; i < (MROWS * ROWP) / 16; i += 256) ((v4i*)ms)[i] = v4i{0, 0, 0, 0};

    const int cb = wid;                 // co-block 0..3 per wave
    const int g  = lane >> 4, li = lane & 15;

    // A-fragments (global, L2-hot) and per-lane channel constants
    v4i a1[9], a2[9];
#pragma unroll
    for (int t = 0; t < 9; ++t) {
        a1[t] = *(const v4i*)(w8 + ((t * 4 + cb) * 64 + lane) * 16);
        a2[t] = *(const v4i*)(w8 + W8SZ + ((t * 4 + cb) * 64 + lane) * 16);
    }
    const float zx   = (float)(*p_zx);
    const float zm   = (float)(*p_zm);
    const float sc1  = ldexpf((float)(*p_M0c1), -31 - (*p_shc1));
    const float sc2  = ldexpf((float)(*p_M0c2), -31 - (*p_shc2));
    const float sa1  = ldexpf((float)(*p_M0a1), -31 - (*p_sha1));
    const float sa2  = ldexpf((float)(*p_M0a2), -31 - (*p_sha2));
    const float zadd = (float)(*p_zadd);
    float bb1[4], gg1[4], bev1[4], sb1[4];
    float bb2[4], gg2[4], bev2[4], sb2[4];
#pragma unroll
    for (int r = 0; r < 4; ++r) {
        int co = cb * 16 + (g << 2) + r;
        bb1[r] = b1[co]; gg1[r] = g1[co]; bev1[r] = be1[co];
        sb1[r] = ldexpf((float)M0b1[co], -31 - shb1[co]);
        bb2[r] = b2[co]; gg2[r] = g2[co]; bev2[r] = be2[co];
        sb2[r] = ldexpf((float)M0b2[co], -31 - shb2[co]);
    }
    __syncthreads();   // zeros visible

    // ---- stage x rows m0-2 .. m0+5 as int8 (x - zx), ci packed in u32 ----
    for (int e = tid; e < XROWS * 16 * 56; e += 256) {
        int L   = e / (16 * 56);
        int rem = e - L * (16 * 56);
        int cq  = rem / 56;
        int w   = rem - cq * 56;
        int hh  = m0 - 2 + L;
        if ((unsigned)hh < 56u) {
            const float* xp = x + ((size_t)(n * Cc + cq * 4) * 56 + hh) * 56 + w;
            unsigned pk = 0;
#pragma unroll
            for (int j = 0; j < 4; ++j) {
                int bv = (int)(xp[(size_t)j * NPIX] - zx);
                pk |= (unsigned)(bv & 255) << (8 * j);
            }
            *(unsigned*)&xs[L * ROWP + (w + 1) * WPITCH + cq * 4] = pk;
        }
    }
    __syncthreads();   // xs ready

    // ---- conv1 + requant + bn1 + requant -> ms (int8) ----
    // 21 px-tiles (6 mid rows x 56), each wave does its cb for all tiles.
#define C1TILE(T)                                                              \
    {                                                                          \
        const int q  = (T) * 16 + li;                                          \
        const int rm = q / 56, w = q - rm * 56;                                \
        const signed char* bp = &xs[rm * ROWP + w * WPITCH + (g << 4)];        \
        v4i bf[9];                                                             \
        _Pragma("unroll")                                                      \
        for (int kh = 0; kh < 3; ++kh) {                                       \
            bf[kh * 3 + 0] = *(const v4i*)(bp + kh * ROWP);                    \
            bf[kh * 3 + 1] = *(const v4i*)(bp + kh * ROWP + WPITCH);           \
            bf[kh * 3 + 2] = *(const v4i*)(bp + kh * ROWP + 2 * WPITCH);       \
        }                                                                      \
        v4i acc = {0, 0, 0, 0};                                                \
        _Pragma("unroll")                                                      \
        for (int t = 0; t < 9; ++t)                                            \
            acc = __builtin_amdgcn_mfma_i32_16x16x64_i8(a1[t], bf[t], acc, 0, 0, 0); \
        const int m = m0 - 1 + rm;                                             \
        if ((unsigned)m < 56u) {                                               \
            unsigned pk = 0;                                                   \
            _Pragma("unroll")                                                  \
            for (int r = 0; r < 4; ++r) {                                      \
                float aa = (float)acc[r] + bb1[r];                             \
                float v  = clamp8(rintf(aa * sc1) + zm);                       \
                float tt = (v - zm) * gg1[r] + bev1[r];                        \
                float u  = clamp8(rintf(tt * sb1[r]) + zm);                    \
                pk |= (unsigned)((int)(u - zm) & 255) << (8 * r);              \
            }                                                                  \
            *(unsigned*)&ms[rm * ROWP + (w + 1) * WPITCH + cb * 16 + (g << 2)] = pk; \
        }                                                                      \
    }
    for (int tp = 0; tp < 20; tp += 2) { C1TILE(tp) C1TILE(tp + 1) }
    C1TILE(20)
#undef C1TILE
    __syncthreads();   // ms ready

    // ---- conv2 + requant + bn2 + requant + shortcut add -> out (f32) ----
#define C2TILE(T)                                                              \
    {                                                                          \
        const int q = (T) * 16 + li;                                           \
        const int j = q / 56, w = q - j * 56;                                  \
        const signed char* bp = &ms[j * ROWP + w * WPITCH + (g << 4)];         \
        v4i bf[9];                                                             \
        _Pragma("unroll")                                                      \
        for (int kh = 0; kh < 3; ++kh) {                                       \
            bf[kh * 3 + 0] = *(const v4i*)(bp + kh * ROWP);                    \
            bf[kh * 3 + 1] = *(const v4i*)(bp + kh * ROWP + WPITCH);           \
            bf[kh * 3 + 2] = *(const v4i*)(bp + kh * ROWP + 2 * WPITCH);       \
        }                                                                      \
        v4i acc = {0, 0, 0, 0};                                                \
        _Pragma("unroll")                                                      \
        for (int t = 0; t < 9; ++t)                                            \
            acc = __builtin_amdgcn_mfma_i32_16x16x64_i8(a2[t], bf[t], acc, 0, 0, 0); \
        const int o = m0 + j;                                                  \
        unsigned id4 = *(const unsigned*)&xs[(j + 2) * ROWP + (w + 1) * WPITCH \
                                             + cb * 16 + (g << 2)];            \
        float* op = out + (size_t)(n * Cc + cb * 16 + (g << 2)) * NPIX         \
                        + o * 56 + w;                                          \
        _Pragma("unroll")                                                      \
        for (int r = 0; r < 4; ++r) {                                          \
            float aa   = (float)acc[r] + bb2[r];                               \
            float v    = clamp8(rintf(aa * sc2) + zm);                         \
            float tt   = (v - zm) * gg2[r] + bev2[r];                          \
            float u    = clamp8(rintf(tt * sb2[r]) + zm);                      \
            float outr = rintf((u - zm) * sa2);                                \
            float idr  = rintf((float)(signed char)(id4 >> (8 * r)) * sa1);    \
            op[(size_t)r * NPIX] = clamp8(idr + outr + zadd);                  \
        }                                                                      \
    }
    for (int tp = 0; tp < 14; tp += 2) { C2TILE(tp) C2TILE(tp + 1) }
#undef C2TILE
}

extern "C" void kernel_launch(void* const* d_in, const int* in_sizes, int n_in,
                              void* d_out, int out_size, void* d_ws, size_t ws_size,
                              hipStream_t stream) {
    const float* x   = (const float*)d_in[0];
    const float* w1  = (const float*)d_in[1];
    const float* b1  = (const float*)d_in[2];
    const float* w2  = (const float*)d_in[3];
    const float* b2  = (const float*)d_in[4];
    const float* g1  = (const float*)d_in[5];
    const float* be1 = (const float*)d_in[6];
    const float* g2  = (const float*)d_in[7];
    const float* be2 = (const float*)d_in[8];
    const int* z_x   = (const int*)d_in[9];
    const int* z_mid = (const int*)d_in[10];
    const int* M0c1  = (const int*)d_in[11];
    const int* shc1  = (const int*)d_in[12];
    const int* M0b1  = (const int*)d_in[13];
    const int* shb1  = (const int*)d_in[14];
    const int* M0c2  = (const int*)d_in[15];
    const int* shc2  = (const int*)d_in[16];
    const int* M0b2  = (const int*)d_in[17];
    const int* shb2  = (const int*)d_in[18];
    const int* M0a1  = (const int*)d_in[19];
    const int* sha1  = (const int*)d_in[20];
    const int* M0a2  = (const int*)d_in[21];
    const int* sha2  = (const int*)d_in[22];
    const int* z_add = (const int*)d_in[23];

    signed char* w8 = (signed char*)d_ws;   // 2 x 36 KB packed A-fragments

    qbb_pack_w<<<dim3(2 * W8SZ / 256), dim3(256), 0, stream>>>(w1, w2, w8);
    qbb_fused<<<dim3(NIMG * TILES), dim3(256), 0, stream>>>(
        x, w8, b1, g1, be1, b2, g2, be2,
        z_x, z_mid, M0c1, shc1, M0b1, shb1, M0c2, shc2, M0b2, shb2,
        M0a1, sha1, M0a2, sha2, z_add, (float*)d_out);
}